// Round 15
// baseline (136.162 us; speedup 1.0000x reference)
//
#include <hip/hip_runtime.h>

typedef __attribute__((ext_vector_type(8))) short bf16x8;
typedef __attribute__((ext_vector_type(4))) float f32x4;
typedef __attribute__((ext_vector_type(16))) float f32x16;

__device__ __forceinline__ unsigned short f2bf(float f) {  // RNE
    union { float f; unsigned u; } v; v.f = f;
    return (unsigned short)((v.u + 0x7FFFu + ((v.u >> 16) & 1u)) >> 16);
}

__device__ __forceinline__ float fexp2(float v) {
#if __has_builtin(__builtin_amdgcn_exp2f)
    return __builtin_amdgcn_exp2f(v);
#else
    float r; asm("v_exp_f32 %0, %1" : "=v"(r) : "v"(v)); return r;
#endif
}
// pack two f32 -> two bf16 (RNE) in one instr (T12 primitive)
__device__ __forceinline__ unsigned cvt_pk_bf16(float lo, float hi) {
    unsigned r;
    asm("v_cvt_pk_bf16_f32 %0, %1, %2" : "=v"(r) : "v"(lo), "v"(hi));
    return r;
}

__device__ __forceinline__ void async16(unsigned short* lds, const unsigned short* gsrc) {
    __builtin_amdgcn_global_load_lds(
        (const __attribute__((address_space(1))) void*)gsrc,
        (__attribute__((address_space(3))) void*)lds, 16, 0, 0);
}

// ---------------- Kernel 0: weight transpose + bf16 cast (swizzled) ------
// kf rows (n<32) pre-scaled by log2(e): softmax exp(s) == exp2(s_scaled).
__global__ __launch_bounds__(256) void k_wt(const float* __restrict__ kf,
                                            const float* __restrict__ kg,
                                            const float* __restrict__ kh,
                                            unsigned short* __restrict__ wt) {
    int n = blockIdx.x, t = threadIdx.x;
    const float* src; int stride, col;
    if (n < 32)      { src = kf; stride = 32;  col = n; }
    else if (n < 64) { src = kg; stride = 32;  col = n - 32; }
    else             { src = kh; stride = 256; col = n - 64; }
    float v = src[t * stride + col];
    if (n < 32) v *= 1.44269504088896341f;     // log2(e)
    wt[n * 256 + (((t >> 3) ^ (n & 7)) << 3) + (t & 7)] = f2bf(v);
}

// ---------------- Kernel 1: projections (R8 body, hT3 k16 store) ---------
// hT3[b][k16][ch][k16lo]: 16-key granule. k_proj store: key>>4 is
// wave-constant, key&15 = n15 -> consecutive lanes write consecutive 2B
// (32B runs; R8's k8 layout scattered 2B at (ch)*8+(key&7) granularity —
// ~256 isolated 2B writes per wave over 8KB, the suspected k_proj cost).
// k_attn PV fragment stays 16B/lane and the full wave covers a contiguous
// 1KB span.
__global__ __launch_bounds__(512) void k_proj(const float* __restrict__ x,
                                              const unsigned short* __restrict__ wt,
                                              unsigned short* __restrict__ f,
                                              unsigned short* __restrict__ g,
                                              unsigned short* __restrict__ hT) {
    __shared__ unsigned short xs[8192];       // 32 x 256 bf16, swizzled  16 KB
    __shared__ unsigned short ws[16384];      // one 64-col W tile        32 KB
    int t = threadIdx.x, rb = blockIdx.x;     // 512 row-blocks of 32 rows
    int w = t >> 6, lane = t & 63, q = lane >> 4, n15 = lane & 15;
    int b = rb >> 7, nbase = (rb & 127) * 32;
    int rg0 = w & 1, cg0 = w >> 1;            // ct0: 2 rowg x 4 colg
    int cgh = w & 3, rgh = w >> 2;            // ct>=1: 4 chg x 2 rowg

#pragma unroll
    for (int i = 0; i < 4; ++i) {
        int lin = i * 512 + t, row = lin >> 6, c4 = lin & 63;
        float4 v = *(const float4*)&x[(rb * 32 + row) * 256 + c4 * 4];
        ushort4 o; o.x = f2bf(v.x); o.y = f2bf(v.y); o.z = f2bf(v.z); o.w = f2bf(v.w);
        *(ushort4*)&xs[row * 256 + (((c4 >> 1) ^ (row & 7)) << 3) + ((c4 & 1) << 2)] = o;
    }
#pragma unroll
    for (int j = 0; j < 4; ++j)
        async16(&ws[(j * 512 + w * 64) * 8], wt + (j * 512 + t) * 8);
    __syncthreads();                           // xs + tile0 ready

    for (int ct = 0; ct < 5; ++ct) {
        f32x4 acc = (f32x4){0.f, 0.f, 0.f, 0.f};
        if (ct == 0) {                         // f,g : D[m=row][n=col]
#pragma unroll
            for (int kk = 0; kk < 8; ++kk) {
                bf16x8 a = *(const bf16x8*)&xs[(rg0 * 16 + n15) * 256
                                + ((((kk << 2) + q) ^ (n15 & 7)) << 3)];
                bf16x8 bw = *(const bf16x8*)&ws[(cg0 * 16 + n15) * 256
                                + ((((kk << 2) + q) ^ (n15 & 7)) << 3)];
                acc = __builtin_amdgcn_mfma_f32_16x16x32_bf16(a, bw, acc, 0, 0, 0);
            }
        } else {                               // h : D[m=ch][n=row] (swapped)
#pragma unroll
            for (int kk = 0; kk < 8; ++kk) {
                bf16x8 a = *(const bf16x8*)&ws[(cgh * 16 + n15) * 256
                                + ((((kk << 2) + q) ^ (n15 & 7)) << 3)];
                bf16x8 bx = *(const bf16x8*)&xs[(rgh * 16 + n15) * 256
                                + ((((kk << 2) + q) ^ (n15 & 7)) << 3)];
                acc = __builtin_amdgcn_mfma_f32_16x16x32_bf16(a, bx, acc, 0, 0, 0);
            }
        }
        __syncthreads();                       // all waves done reading ws
        if (ct < 4) {                          // DMA tile ct+1 (flies over stores)
            const unsigned short* wsrc = wt + (ct + 1) * 16384;
#pragma unroll
            for (int j = 0; j < 4; ++j)
                async16(&ws[(j * 512 + w * 64) * 8], wsrc + (j * 512 + t) * 8);
        }
        if (ct == 0) {                         // store f/g (overlaps DMA)
#pragma unroll
            for (int r = 0; r < 4; ++r) {
                int grow = rb * 32 + rg0 * 16 + q * 4 + r;
                int col = cg0 * 16 + n15;
                unsigned short v = f2bf(acc[r]);
                if (col < 32) f[grow * 32 + col] = v;
                else          g[grow * 32 + (col - 32)] = v;
            }
        } else {                               // store hT3 (overlaps DMA)
#pragma unroll
            for (int r = 0; r < 4; ++r) {
                int ch = (ct - 1) * 64 + cgh * 16 + q * 4 + r;
                int key = nbase + rgh * 16 + n15;
                hT[((b * 256 + (key >> 4)) * 256 + ch) * 16 + (key & 15)] = f2bf(acc[r]);
            }
        }
        __syncthreads();                       // tile ct+1 landed
    }
}

// ---------------- Kernel 2: fused flash attention + residual -------------
// EXACT R8/R14 body (session-best, k_attn 56.0 us verified) with only the
// hb2 base formula updated for the hT3 k16 layout (loop offsets identical:
// k16 stride = 4096 shorts, kt stride = 16384 shorts).
__global__ __launch_bounds__(512, 4) void k_attn(const float* __restrict__ x,
                                                 const unsigned short* __restrict__ f,
                                                 const unsigned short* __restrict__ g,
                                                 const unsigned short* __restrict__ hT,
                                                 const float* __restrict__ gamma_p,
                                                 float* __restrict__ out) {
    __shared__ unsigned short pls[2][4096];    // P dbuf: 64 rows x 64 keys 16 KB
    __shared__ float lpart[4][64];             // per-S-wave key-partial row sums
    __shared__ __align__(16) float lrec[64];   // per-row 1/l
    int t = threadIdx.x, bx = blockIdx.x;
    int b = (bx >> 1) & 3;                     // one batch per XCD-pair
    int ch2 = (bx >> 3) & 1;                   // channel half (128 ch)
    int qt = ((bx & 1) << 5) | (bx >> 4);      // 64 Q-tiles of 64 rows
    int qbase = qt * 64;
    int chbase = ch2 * 128;
    int w = t >> 6, l = t & 63;
    int hi = l >> 5, l31 = l & 31;             // 32x32 roles (PV)
    int q = l >> 4, n15 = l & 15;              // 16x16 roles (S)
    int cb = w & 3;                            // PV ch-block (w>=4)
    const bool is_s = (w < 4);

    // ---- S-wave state: key-split. Wave w owns keys [kt*64+w*16, +16). ----
    bf16x8 aFB[4];
    const unsigned short* gW = g + (b * 4096 + w * 16 + n15) * 32 + q * 8;  // +kt*2048
    if (is_s) {
#pragma unroll
        for (int nt = 0; nt < 4; ++nt)
            aFB[nt] = *(const bf16x8*)&f[(b * 4096 + qbase + nt * 16 + n15) * 32 + q * 8];
    }
    bf16x8 aG, aGn;
    f32x4 lac = (f32x4){0.f, 0.f, 0.f, 0.f};   // l partials per nt (row group)
    const f32x4 zero4 = (f32x4){0.f, 0.f, 0.f, 0.f};

    // ---- PV-wave state: coalesced hT3 pointer + reg dbuf ----
    // hT3 idx = ((b*256 + k16)*256 + ch)*16 + k16lo ; k16 = kt*4 + ks,
    // k16lo = hi*8. Fragment = hb2 + kt*16384 + ks*4096 (shorts).
    const unsigned short* hb2 = hT + b * 1048576
                              + (chbase + cb * 32 + l31) * 16 + hi * 8;
    bf16x8 bHc[4], bHn[4];

    // S-step for tile in aG -> pls[buf].
    // D[m=key w*16+4q+r][n=qrow nt*16+n15]; key-quad kq = 4w+q.
    auto s_tile = [&](int buf) {
        f32x4 sa[4];
#pragma unroll
        for (int nt = 0; nt < 4; ++nt)
            sa[nt] = __builtin_amdgcn_mfma_f32_16x16x32_bf16(aG, aFB[nt], zero4, 0, 0, 0);
        int kq = w * 4 + q;
#pragma unroll
        for (int nt = 0; nt < 4; ++nt) {
#pragma unroll
            for (int r = 0; r < 4; ++r) {
                sa[nt][r] = fexp2(sa[nt][r]);  // f pre-scaled by log2(e)
                lac[nt] += sa[nt][r];
            }
            unsigned p0 = cvt_pk_bf16(sa[nt][0], sa[nt][1]);
            unsigned p1 = cvt_pk_bf16(sa[nt][2], sa[nt][3]);
            int row = nt * 16 + n15;
            // phys = row*128B + ((kq>>1)^(row&7))*16B + (kq&1)*8B
            unsigned* dst = (unsigned*)&pls[buf][row * 64]
                          + (((kq >> 1) ^ (n15 & 7)) << 2) + ((kq & 1) << 1);
            dst[0] = p0; dst[1] = p1;
        }
    };

    f32x16 o0, o1;
#pragma unroll
    for (int i = 0; i < 16; ++i) { o0[i] = 0.f; o1[i] = 0.f; }

    // ---- prologue: S(0) -> pls[0]; PV loads bH(0); aG <- tile 1 ----
    if (is_s) {
        aG  = *(const bf16x8*)&gW[0];
        aGn = *(const bf16x8*)&gW[2048];
        s_tile(0);
        aG = aGn;
        __builtin_amdgcn_sched_barrier(0);
        asm volatile("s_waitcnt lgkmcnt(0)" ::: "memory");
    } else {
#pragma unroll
        for (int ks = 0; ks < 4; ++ks)
            bHc[ks] = *(const bf16x8*)&hb2[ks * 4096];
        __builtin_amdgcn_sched_barrier(0);
    }
    __builtin_amdgcn_s_barrier();              // publishes pls[0]
    __builtin_amdgcn_sched_barrier(0);

#pragma unroll 2
    for (int kt = 0; kt < 64; ++kt) {
        int cur = kt & 1, nxt = cur ^ 1;

        if (is_s) {
            if (kt + 1 < 64) {
                int ktn = (kt + 2 < 64) ? kt + 2 : 63;
                aGn = *(const bf16x8*)&gW[ktn * 2048];   // flies during s_tile
                s_tile(nxt);                             // S(kt+1) from aG
                aG = aGn;
            }
            __builtin_amdgcn_sched_barrier(0);
            asm volatile("s_waitcnt lgkmcnt(0)" ::: "memory");  // pls[nxt] visible
        } else {
            if (kt + 1 < 64) {                 // issue bH(kt+1) early (T14)
#pragma unroll
                for (int ks = 0; ks < 4; ++ks)
                    bHn[ks] = *(const bf16x8*)&hb2[(kt + 1) * 16384 + ks * 4096];
            }
            // ---- O += P(kt).H(kt) : 32x32x16, 4 key-steps ----
            const unsigned short* pcur = &pls[cur][0];
            __builtin_amdgcn_s_setprio(1);
#pragma unroll
            for (int ks = 0; ks < 4; ++ks) {
                int seg = (((2 * ks + hi) ^ (l31 & 7)) << 3);
                bf16x8 aP0 = *(const bf16x8*)&pcur[l31 * 64 + seg];
                bf16x8 aP1 = *(const bf16x8*)&pcur[(32 + l31) * 64 + seg];
                o0 = __builtin_amdgcn_mfma_f32_32x32x16_bf16(aP0, bHc[ks], o0, 0, 0, 0);
                o1 = __builtin_amdgcn_mfma_f32_32x32x16_bf16(aP1, bHc[ks], o1, 0, 0, 0);
            }
            __builtin_amdgcn_s_setprio(0);
            if (kt + 1 < 64) {
#pragma unroll
                for (int ks = 0; ks < 4; ++ks) bHc[ks] = bHn[ks];
            }
            __builtin_amdgcn_sched_barrier(0);
        }

        __builtin_amdgcn_s_barrier();          // publish pls[nxt]
        __builtin_amdgcn_sched_barrier(0);
    }

    // ---- epilogue: l reduce (4 key-partials per row), O/l, residual ----
    if (is_s) {
#pragma unroll
        for (int nt = 0; nt < 4; ++nt) {
            float ps = lac[nt];
            ps += __shfl_xor(ps, 16);
            ps += __shfl_xor(ps, 32);
            if (q == 0) lpart[w][nt * 16 + n15] = ps;
        }
    }
    __syncthreads();
    if (t < 64) lrec[t] = 1.0f / (lpart[0][t] + lpart[1][t] + lpart[2][t] + lpart[3][t]);
    __syncthreads();
    if (!is_s) {
        float gam = *gamma_p;
        int ch = chbase + cb * 32 + l31;
#pragma unroll
        for (int qq = 0; qq < 4; ++qq) {
            int r0 = 8 * qq + 4 * hi;
            f32x4 ri0 = *(const f32x4*)&lrec[r0];
            f32x4 ri1 = *(const f32x4*)&lrec[32 + r0];
#pragma unroll
            for (int j = 0; j < 4; ++j) {
                int idx0 = (b * 4096 + qbase + r0 + j) * 256 + ch;
                int idx1 = idx0 + 32 * 256;
                out[idx0] = x[idx0] + gam * (o0[4 * qq + j] * ri0[j]);
                out[idx1] = x[idx1] + gam * (o1[4 * qq + j] * ri1[j]);
            }
        }
    }
}

// ---------------- launch ------------------------------------------------
extern "C" void kernel_launch(void* const* d_in, const int* in_sizes, int n_in,
                              void* d_out, int out_size, void* d_ws, size_t ws_size,
                              hipStream_t stream) {
    const float* x  = (const float*)d_in[0];
    const float* kf = (const float*)d_in[1];
    const float* kg = (const float*)d_in[2];
    const float* kh = (const float*)d_in[3];
    const float* gm = (const float*)d_in[4];
    float* out = (float*)d_out;

    char* ws = (char*)d_ws;
    unsigned short* wt = (unsigned short*)(ws);             // 320*256*2   = 163840 B
    unsigned short* fb = (unsigned short*)(ws + 163840);    // 16384*32*2  = 1 MiB
    unsigned short* gb = (unsigned short*)(ws + 1212416);   // 16384*32*2  = 1 MiB
    unsigned short* hT = (unsigned short*)(ws + 2260992);   // 4*256*256*16*2 = 8 MiB

    hipLaunchKernelGGL(k_wt,   dim3(320), dim3(256), 0, stream, kf, kg, kh, wt);
    hipLaunchKernelGGL(k_proj, dim3(512), dim3(512), 0, stream, x, wt, fb, gb, hT);
    hipLaunchKernelGGL(k_attn, dim3(512), dim3(512), 0, stream, x, fb, gb, hT, gm, out);
}